// Round 7
// baseline (119.310 us; speedup 1.0000x reference)
//
#include <hip/hip_runtime.h>
#include <hip/hip_bf16.h>
#include <stdint.h>

// Problem dims (fixed by reference setup_inputs)
#define BQ   8192   // query rows
#define DIM  1024   // feature dim
#define NK   2048   // number of keys/values

typedef unsigned short u16;
using f32x4  = __attribute__((ext_vector_type(4))) float;
using bf16x8 = __attribute__((ext_vector_type(8))) __bf16;
using f16x8  = __attribute__((ext_vector_type(8))) _Float16;
using u16x4  = __attribute__((ext_vector_type(4))) unsigned short;
using u16x8  = __attribute__((ext_vector_type(8))) unsigned short;

// ---------- helpers ----------

__device__ __forceinline__ u16 f2bf(float f) {
    // round-to-nearest-even fp32 -> bf16
    uint32_t u = __float_as_uint(f);
    u += 0x7FFFu + ((u >> 16) & 1u);
    return (u16)(u >> 16);
}

__device__ __forceinline__ u16 f2h(float f) {
    _Float16 h = (_Float16)f;             // v_cvt_f16_f32 (RTN)
    return __builtin_bit_cast(unsigned short, h);
}

__device__ __forceinline__ void gload_lds16(const void* g, void* l) {
    __builtin_amdgcn_global_load_lds(
        (const __attribute__((address_space(1))) void*)g,
        (__attribute__((address_space(3))) void*)l,
        16, 0, 0);
}

template<bool F16>
__device__ __forceinline__ f32x4 mfmaT(u16x8 a, u16x8 b, f32x4 c) {
    if constexpr (F16)
        return __builtin_amdgcn_mfma_f32_16x16x32_f16(
            __builtin_bit_cast(f16x8, a), __builtin_bit_cast(f16x8, b), c, 0, 0, 0);
    else
        return __builtin_amdgcn_mfma_f32_16x16x32_bf16(
            __builtin_bit_cast(bf16x8, a), __builtin_bit_cast(bf16x8, b), c, 0, 0, 0);
}

// ---------- stage 0: fp32 -> bf16 convert (Q and K in one kernel) ----------

__global__ void cvt_qk(const float* __restrict__ Q, const float* __restrict__ K,
                       u16* __restrict__ Qb, u16* __restrict__ Kb, int n4Q, int n4T) {
    int i = blockIdx.x * blockDim.x + threadIdx.x;
    if (i >= n4T) return;
    const float* src; u16* dst; int j;
    if (i < n4Q) { src = Q; dst = Qb; j = i; }
    else         { src = K; dst = Kb; j = i - n4Q; }
    f32x4 v = reinterpret_cast<const f32x4*>(src)[j];
    u16x4 o;
    o.x = f2bf(v[0]); o.y = f2bf(v[1]); o.z = f2bf(v[2]); o.w = f2bf(v[3]);
    reinterpret_cast<u16x4*>(dst)[j] = o;
}

// transpose V (NK x DIM fp32) -> VT (DIM x NK fp16)
__global__ void transpose_cvt(const float* __restrict__ V, u16* __restrict__ VT) {
    __shared__ float tile[32][33];
    int d0 = blockIdx.x * 32;
    int n0 = blockIdx.y * 32;
    int tx = threadIdx.x, ty = threadIdx.y;
#pragma unroll
    for (int i = 0; i < 4; ++i)
        tile[ty + i * 8][tx] = V[(size_t)(n0 + ty + i * 8) * DIM + d0 + tx];
    __syncthreads();
#pragma unroll
    for (int i = 0; i < 4; ++i)
        VT[(size_t)(d0 + ty + i * 8) * NK + n0 + tx] = f2h(tile[tx][ty + i * 8]);
}

// ---------- 128x128 GEMM, 2 blocks/CU: C[M,N] = scale * A[M,K]*B[N,K]^T ----------
// 4 waves (2x2 of 64x64), BK=64, double-buffered LDS (64 KiB -> 2 blocks/CU so
// barrier-drain stalls of one block are hidden by the other), stage for t+1
// issued at top of iter t, T2 XOR-swizzled LDS (inverse-swizzled global source
// + swizzled ds_read; identical formulas to the verified 256-sq version),
// setprio around MFMA clusters, bijective XCD block swizzle.
// F16 selects fp16-input MFMA (else bf16). Grid must be a multiple of 8.

template<bool F16, typename OT>
__global__ __launch_bounds__(256, 2)
void gemm128(const u16* __restrict__ A, const u16* __restrict__ B, OT* __restrict__ C,
             int K, int lda, int ldb, int ldc, float scale, int nbn) {
    __shared__ u16 As[2][128 * 64];
    __shared__ u16 Bs[2][128 * 64];

    const int tid  = threadIdx.x;
    const int wave = tid >> 6;      // 0..3
    const int lane = tid & 63;
    const int wr = wave >> 1;       // 0..1
    const int wc = wave & 1;        // 0..1

    // XCD-aware bijective swizzle (grid is a multiple of 8)
    int id = blockIdx.x;
    const int cpx = gridDim.x >> 3;
    id = (id & 7) * cpx + (id >> 3);
    const int bm = id / nbn;
    const int bn = id % nbn;

    // ---- staging geometry: one gload instr per wave = 8 rows x 128B = 1 KiB ----
    const int lsub  = lane >> 3;                 // row within 8-row chunk (0..7)
    const int lslot = lane & 7;                  // 16B slot within 128B row
    const int srcColEl = ((lslot ^ lsub) << 3);  // inverse-swizzled k offset (elements)

    const u16* aSrc = A + (size_t)(bm * 128 + wave * 8 + lsub) * lda + srcColEl;
    const u16* bSrc = B + (size_t)(bn * 128 + wave * 8 + lsub) * ldb + srcColEl;
    const int dst0 = (wave * 8) * 64;            // u16 offset of wave's 1KB slice

    auto STAGE = [&](int buf, int kt) {
        const size_t ko = (size_t)kt * 64;
#pragma unroll
        for (int c = 0; c < 4; ++c) {            // c*32 rows apart (4 waves cover 32)
            gload_lds16(aSrc + (size_t)(c * 32) * lda + ko, &As[buf][dst0 + c * 32 * 64]);
            gload_lds16(bSrc + (size_t)(c * 32) * ldb + ko, &Bs[buf][dst0 + c * 32 * 64]);
        }
    };

    // ---- swizzled fragment reads (row stride 128B; byte ^= (row&7)<<4) ----
    const int fr = lane & 15;
    auto LDA_frag = [&](int buf, int m, int kk) -> u16x8 {
        int r   = wr * 64 + m * 16 + fr;
        int off = r * 128 + ((kk * 64 + ((lane >> 4) << 4)) ^ ((lane & 7) << 4));
        return *reinterpret_cast<const u16x8*>(
            reinterpret_cast<const char*>(&As[buf][0]) + off);
    };
    auto LDB_frag = [&](int buf, int n, int kk) -> u16x8 {
        int r   = wc * 64 + n * 16 + fr;
        int off = r * 128 + ((kk * 64 + ((lane >> 4) << 4)) ^ ((lane & 7) << 4));
        return *reinterpret_cast<const u16x8*>(
            reinterpret_cast<const char*>(&Bs[buf][0]) + off);
    };

    f32x4 acc[4][4] = {};
    const int NT = K >> 6;

    STAGE(0, 0);
    __syncthreads();          // tile 0 published

    int cbuf = 0;
    for (int t = 0; t < NT; ++t) {
        if (t + 1 < NT) STAGE(cbuf ^ 1, t + 1);   // drained by end-of-iter barrier
        __builtin_amdgcn_sched_barrier(0);

#pragma unroll
        for (int kk = 0; kk < 2; ++kk) {
            u16x8 af[4], bf[4];
#pragma unroll
            for (int m = 0; m < 4; ++m) af[m] = LDA_frag(cbuf, m, kk);
#pragma unroll
            for (int n = 0; n < 4; ++n) bf[n] = LDB_frag(cbuf, n, kk);
            __builtin_amdgcn_s_setprio(1);
#pragma unroll
            for (int m = 0; m < 4; ++m)
#pragma unroll
                for (int n = 0; n < 4; ++n)
                    acc[m][n] = mfmaT<F16>(af[m], bf[n], acc[m][n]);
            __builtin_amdgcn_s_setprio(0);
        }

        __syncthreads();      // drains (aged) stage of t+1 + publishes it
        cbuf ^= 1;
    }

    // epilogue: C/D layout col = lane&15, row = (lane>>4)*4 + j
    const int col0 = bn * 128 + wc * 64 + fr;
    const int row0 = bm * 128 + wr * 64 + ((lane >> 4) << 2);
#pragma unroll
    for (int m = 0; m < 4; ++m) {
#pragma unroll
        for (int j = 0; j < 4; ++j) {
            int row = row0 + m * 16 + j;
            OT* cp = C + (size_t)row * ldc + col0;
#pragma unroll
            for (int n = 0; n < 4; ++n)
                cp[n * 16] = (OT)(acc[m][n][j] * scale);
        }
    }
}

// ---------- stage 2: wave-per-row softmax1 + 16-step sigmoid long-division ----------
// S fp16 (BQ x NK) -> W fp16 (BQ x NK). 4 waves/block = 4 rows/block, no LDS.

__global__ __launch_bounds__(256)
void softmax_recip_f16(const u16* __restrict__ S, u16* __restrict__ W) {
    const int lane = threadIdx.x & 63;
    const int row  = blockIdx.x * 4 + (threadIdx.x >> 6);

    const u16x8* sp = reinterpret_cast<const u16x8*>(S + (size_t)row * NK);
    u16x8 raw[4];
#pragma unroll
    for (int j = 0; j < 4; ++j) raw[j] = sp[lane + j * 64];   // coalesced 16B/lane

    float e[32];
    float mx = -1e30f;
#pragma unroll
    for (int j = 0; j < 4; ++j)
#pragma unroll
        for (int i = 0; i < 8; ++i) {
            float f = (float)__builtin_bit_cast(_Float16, (unsigned short)raw[j][i]);
            e[j * 8 + i] = f;
            mx = fmaxf(mx, f);
        }
#pragma unroll
    for (int off = 32; off; off >>= 1) mx = fmaxf(mx, __shfl_xor(mx, off));

    float sum = 0.f;
#pragma unroll
    for (int i = 0; i < 32; ++i) { e[i] = expf(e[i] - mx); sum += e[i]; }
#pragma unroll
    for (int off = 32; off; off >>= 1) sum += __shfl_xor(sum, off);

    const float d = 1.0f + sum;

    // non-restoring long division, 16 bits, soft comparator sigmoid(100*(2r - d))
    float r = 1.0f, q = 0.0f, w = 0.5f;
#pragma unroll
    for (int i = 0; i < 16; ++i) {
        float doubled = 2.0f * r;
        float st = 1.0f / (1.0f + expf(-100.0f * (doubled - d)));
        r = doubled - d * st;
        q += w * st;
        w *= 0.5f;
    }

    u16x8* wp = reinterpret_cast<u16x8*>(W + (size_t)row * NK);
#pragma unroll
    for (int j = 0; j < 4; ++j) {
        u16x8 o;
#pragma unroll
        for (int i = 0; i < 8; ++i) o[i] = f2h(e[j * 8 + i] * q);
        wp[lane + j * 64] = o;
    }
}

// ---------- launch ----------

extern "C" void kernel_launch(void* const* d_in, const int* in_sizes, int n_in,
                              void* d_out, int out_size, void* d_ws, size_t ws_size,
                              hipStream_t stream) {
    const float* Q = (const float*)d_in[0];
    const float* K = (const float*)d_in[1];
    const float* V = (const float*)d_in[2];
    float* out = (float*)d_out;

    char* ws = (char*)d_ws;
    // ws layout (bytes):
    //   Qb  bf16 8192x1024 : 16 MiB
    //   Kb  bf16 2048x1024 :  4 MiB
    //   VhT fp16 1024x2048 :  4 MiB
    //   S   fp16 8192x2048 : 32 MiB
    //   W   fp16 8192x2048 : 32 MiB   -> total 88 MiB
    u16* Qb  = (u16*)(ws);
    u16* Kb  = (u16*)(ws + (16u << 20));
    u16* VhT = (u16*)(ws + (20u << 20));
    u16* S   = (u16*)(ws + (24u << 20));
    u16* W   = (u16*)(ws + (56u << 20));

    // stage 0: converts (Q+K fused) and V transpose
    {
        int n4Q = BQ * DIM / 4;
        int n4T = n4Q + NK * DIM / 4;
        cvt_qk<<<(n4T + 255) / 256, 256, 0, stream>>>(Q, K, Qb, Kb, n4Q, n4T);
    }
    transpose_cvt<<<dim3(DIM / 32, NK / 32), dim3(32, 8), 0, stream>>>(V, VhT);

    // stage 1: S(fp16) = (1/32) * Qb @ Kb^T   (M=8192, N=2048, K=1024) — 1024 blocks
    gemm128<false, _Float16><<<(BQ / 128) * (NK / 128), 256, 0, stream>>>(
        Qb, Kb, (_Float16*)S, DIM, DIM, DIM, NK, 0.03125f, NK / 128);

    // stage 2: softmax1 + reciprocal scan -> W fp16 (wave per row)
    softmax_recip_f16<<<BQ / 4, 256, 0, stream>>>(S, W);

    // stage 3: out = W @ VhT^T (f16 MFMA)     (M=8192, N=1024, K=2048) — 512 blocks
    gemm128<true, float><<<(BQ / 128) * (DIM / 128), 256, 0, stream>>>(
        W, VhT, out, NK, NK, NK, DIM, 1.0f, DIM / 128);
}

// Round 8
// 108.251 us; speedup vs baseline: 1.1022x; 1.1022x over previous
//
#include <hip/hip_runtime.h>
#include <hip/hip_bf16.h>
#include <stdint.h>
#include <math.h>

// Problem dims (fixed by reference setup_inputs)
#define BQ   8192   // query rows
#define DIM  1024   // feature dim
#define NK   2048   // number of keys/values

typedef unsigned short u16;
using f32x4  = __attribute__((ext_vector_type(4))) float;
using bf16x8 = __attribute__((ext_vector_type(8))) __bf16;
using f16x8  = __attribute__((ext_vector_type(8))) _Float16;
using u16x4  = __attribute__((ext_vector_type(4))) unsigned short;
using u16x8  = __attribute__((ext_vector_type(8))) unsigned short;

#define EXP_BIAS 4.0f   // E = exp(s - EXP_BIAS); rescaled exactly in stats kernel

// ---------- helpers ----------

__device__ __forceinline__ u16 f2bf(float f) {
    // round-to-nearest-even fp32 -> bf16
    uint32_t u = __float_as_uint(f);
    u += 0x7FFFu + ((u >> 16) & 1u);
    return (u16)(u >> 16);
}

__device__ __forceinline__ u16 f2h(float f) {
    _Float16 h = (_Float16)f;             // v_cvt_f16_f32 (RTN)
    return __builtin_bit_cast(unsigned short, h);
}

__device__ __forceinline__ void gload_lds16(const void* g, void* l) {
    __builtin_amdgcn_global_load_lds(
        (const __attribute__((address_space(1))) void*)g,
        (__attribute__((address_space(3))) void*)l,
        16, 0, 0);
}

template<bool F16>
__device__ __forceinline__ f32x4 mfmaT(u16x8 a, u16x8 b, f32x4 c) {
    if constexpr (F16)
        return __builtin_amdgcn_mfma_f32_16x16x32_f16(
            __builtin_bit_cast(f16x8, a), __builtin_bit_cast(f16x8, b), c, 0, 0, 0);
    else
        return __builtin_amdgcn_mfma_f32_16x16x32_bf16(
            __builtin_bit_cast(bf16x8, a), __builtin_bit_cast(bf16x8, b), c, 0, 0, 0);
}

// ---------- stage 0: fp32 -> bf16 convert (Q and K in one kernel) ----------

__global__ void cvt_qk(const float* __restrict__ Q, const float* __restrict__ K,
                       u16* __restrict__ Qb, u16* __restrict__ Kb, int n4Q, int n4T) {
    int i = blockIdx.x * blockDim.x + threadIdx.x;
    if (i >= n4T) return;
    const float* src; u16* dst; int j;
    if (i < n4Q) { src = Q; dst = Qb; j = i; }
    else         { src = K; dst = Kb; j = i - n4Q; }
    f32x4 v = reinterpret_cast<const f32x4*>(src)[j];
    u16x4 o;
    o.x = f2bf(v[0]); o.y = f2bf(v[1]); o.z = f2bf(v[2]); o.w = f2bf(v[3]);
    reinterpret_cast<u16x4*>(dst)[j] = o;
}

// transpose V (NK x DIM fp32) -> VT (DIM x NK fp16)
__global__ void transpose_cvt(const float* __restrict__ V, u16* __restrict__ VT) {
    __shared__ float tile[32][33];
    int d0 = blockIdx.x * 32;
    int n0 = blockIdx.y * 32;
    int tx = threadIdx.x, ty = threadIdx.y;
#pragma unroll
    for (int i = 0; i < 4; ++i)
        tile[ty + i * 8][tx] = V[(size_t)(n0 + ty + i * 8) * DIM + d0 + tx];
    __syncthreads();
#pragma unroll
    for (int i = 0; i < 4; ++i)
        VT[(size_t)(d0 + ty + i * 8) * NK + n0 + tx] = f2h(tile[tx][ty + i * 8]);
}

// ---------- GEMM (measured-best structure): C[M,N] = f(scale * A[M,K]*B[N,K]^T) ----------
// BM=256, BN in {256,128}. 8 waves (2M x 4N), wave tile 128 x BN/4, BK=64,
// double-buffered LDS, stage for t+1 issued at top of iter t (drained by the
// tile-boundary __syncthreads after 4 MFMA phases), T2 XOR-swizzled LDS
// (inverse-swizzled global source + swizzled ds_read), setprio around MFMA
// clusters, bijective XCD block swizzle. F16 selects fp16-input MFMA (else bf16).
// EXPOUT: out = exp(acc*scale - EXP_BIAS). rowFactor (may be null): out *= rowFactor[row].

template<int BN, bool F16, bool EXPOUT, typename OT>
__global__ __launch_bounds__(512, 2)
void gemm256(const u16* __restrict__ A, const u16* __restrict__ B, OT* __restrict__ C,
             const float* __restrict__ rowFactor,
             int K, int lda, int ldb, int ldc, float scale, int nbn) {
    constexpr int WTN  = BN / 4;    // per-wave N span (64 or 32)
    constexpr int NREP = BN / 64;   // N fragments per wave (4 or 2)
    constexpr int NH   = NREP / 2;  // frags per N-half (2 or 1)
    constexpr int BCALLS = (BN == 256) ? 4 : 2;

    __shared__ u16 As[2][256 * 64];
    __shared__ u16 Bs[2][BN * 64];

    const int tid  = threadIdx.x;
    const int wave = tid >> 6;
    const int lane = tid & 63;
    const int wr = wave >> 2;       // 0..1
    const int wc = wave & 3;        // 0..3

    // XCD-aware bijective swizzle (grid is a multiple of 8)
    int id = blockIdx.x;
    const int cpx = gridDim.x >> 3;
    id = (id & 7) * cpx + (id >> 3);
    const int bm = id / nbn;
    const int bn = id % nbn;

    // ---- staging geometry (each gload call: 8 rows x 128B = 1 KiB) ----
    const int lsub  = lane >> 3;                 // row within 8-row chunk
    const int lslot = lane & 7;                  // 16B slot within 128B row
    const int srcColEl = ((lslot ^ lsub) << 3);  // inverse-swizzled k offset (elements)

    const int aRow0 = wr * 128 + wc * 32;        // wave's A chunk rows (+c*8)
    int bRow0;
    if constexpr (BN == 256) bRow0 = (wc >> 1) * 128 + (wr * 2 + (wc & 1)) * 32;
    else                     bRow0 = wave * 16;

    const u16* aSrc = A + (size_t)(bm * 256 + aRow0 + lsub) * lda + srcColEl;
    const u16* bSrc = B + (size_t)(bn * BN  + bRow0 + lsub) * ldb + srcColEl;

    f32x4 acc[8][NREP] = {};

    const int NT = K >> 6;

    auto STAGE = [&](int buf, int kt) {
        const size_t ko = (size_t)kt * 64;
#pragma unroll
        for (int c2 = 0; c2 < 4; ++c2)
            gload_lds16(aSrc + (size_t)c2 * 8 * lda + ko, &As[buf][(aRow0 + c2 * 8) * 64]);
#pragma unroll
        for (int c2 = 0; c2 < BCALLS; ++c2)
            gload_lds16(bSrc + (size_t)c2 * 8 * ldb + ko, &Bs[buf][(bRow0 + c2 * 8) * 64]);
    };

    // swizzled fragment loads (row stride 128B; byte ^= (row&7)<<4)
    auto LDA_frag = [&](const char* base, int m, int kk) -> u16x8 {
        int r   = wr * 128 + m * 16 + (lane & 15);
        int off = r * 128 + (((kk * 64) + ((lane >> 4) << 4)) ^ ((lane & 7) << 4));
        return *reinterpret_cast<const u16x8*>(base + off);
    };
    auto LDB_frag = [&](const char* base, int n, int kk) -> u16x8 {
        int r   = wc * WTN + n * 16 + (lane & 15);
        int off = r * 128 + (((kk * 64) + ((lane >> 4) << 4)) ^ ((lane & 7) << 4));
        return *reinterpret_cast<const u16x8*>(base + off);
    };

    STAGE(0, 0);
    __syncthreads();          // drain prologue stage; tile 0 published

    int cbuf = 0;
    for (int t = 0; t < NT; ++t) {
        if (t + 1 < NT) STAGE(cbuf ^ 1, t + 1);   // aged across this tile's 4 phases
        __builtin_amdgcn_sched_barrier(0);

        const char* aB = (const char*)&As[cbuf][0];
        const char* bB = (const char*)&Bs[cbuf][0];

        u16x8 af[4][2];
        u16x8 bf0[NH][2], bf1[NH][2];

        // ---- phase 0: A(mh=0) + B(nh=0), MFMA Q(0,0) ----
#pragma unroll
        for (int mi = 0; mi < 4; ++mi) { af[mi][0] = LDA_frag(aB, mi, 0); af[mi][1] = LDA_frag(aB, mi, 1); }
#pragma unroll
        for (int ni = 0; ni < NH; ++ni) { bf0[ni][0] = LDB_frag(bB, ni, 0); bf0[ni][1] = LDB_frag(bB, ni, 1); }
        __builtin_amdgcn_s_setprio(1);
#pragma unroll
        for (int mi = 0; mi < 4; ++mi)
#pragma unroll
            for (int ni = 0; ni < NH; ++ni) {
                acc[mi][ni] = mfmaT<F16>(af[mi][0], bf0[ni][0], acc[mi][ni]);
                acc[mi][ni] = mfmaT<F16>(af[mi][1], bf0[ni][1], acc[mi][ni]);
            }
        __builtin_amdgcn_s_setprio(0);

        // ---- phase 1: B(nh=1), MFMA Q(0,1) ----
#pragma unroll
        for (int ni = 0; ni < NH; ++ni) { bf1[ni][0] = LDB_frag(bB, NH + ni, 0); bf1[ni][1] = LDB_frag(bB, NH + ni, 1); }
        __builtin_amdgcn_s_setprio(1);
#pragma unroll
        for (int mi = 0; mi < 4; ++mi)
#pragma unroll
            for (int ni = 0; ni < NH; ++ni) {
                acc[mi][NH + ni] = mfmaT<F16>(af[mi][0], bf1[ni][0], acc[mi][NH + ni]);
                acc[mi][NH + ni] = mfmaT<F16>(af[mi][1], bf1[ni][1], acc[mi][NH + ni]);
            }
        __builtin_amdgcn_s_setprio(0);

        // ---- phase 2: A(mh=1), MFMA Q(1,1) ----
#pragma unroll
        for (int mi = 0; mi < 4; ++mi) { af[mi][0] = LDA_frag(aB, 4 + mi, 0); af[mi][1] = LDA_frag(aB, 4 + mi, 1); }
        __builtin_amdgcn_s_setprio(1);
#pragma unroll
        for (int mi = 0; mi < 4; ++mi)
#pragma unroll
            for (int ni = 0; ni < NH; ++ni) {
                acc[4 + mi][NH + ni] = mfmaT<F16>(af[mi][0], bf1[ni][0], acc[4 + mi][NH + ni]);
                acc[4 + mi][NH + ni] = mfmaT<F16>(af[mi][1], bf1[ni][1], acc[4 + mi][NH + ni]);
            }
        __builtin_amdgcn_s_setprio(0);

        // ---- phase 3: MFMA Q(1,0) (reuses bf0) ----
        __builtin_amdgcn_s_setprio(1);
#pragma unroll
        for (int mi = 0; mi < 4; ++mi)
#pragma unroll
            for (int ni = 0; ni < NH; ++ni) {
                acc[4 + mi][ni] = mfmaT<F16>(af[mi][0], bf0[ni][0], acc[4 + mi][ni]);
                acc[4 + mi][ni] = mfmaT<F16>(af[mi][1], bf0[ni][1], acc[4 + mi][ni]);
            }
        __builtin_amdgcn_s_setprio(0);

        __syncthreads();      // drains (aged) stage of t+1 + publishes it; frees cbuf
        cbuf ^= 1;
    }

    // epilogue: C/D layout col = lane&15, row = (lane>>4)*4 + j
    const int col0 = bn * BN + wc * WTN + (lane & 15);
    const int row0 = bm * 256 + wr * 128 + ((lane >> 4) << 2);
#pragma unroll
    for (int m = 0; m < 8; ++m) {
#pragma unroll
        for (int j = 0; j < 4; ++j) {
            int row = row0 + m * 16 + j;
            float rf = (rowFactor != nullptr) ? rowFactor[row] : 1.0f;
            OT* cp = C + (size_t)row * ldc + col0;
#pragma unroll
            for (int n = 0; n < NREP; ++n) {
                float v = acc[m][n][j] * scale;
                if constexpr (EXPOUT) v = expf(v - EXP_BIAS);
                cp[n * 16] = (OT)(v * rf);
            }
        }
    }
}

// ---------- stage 2: row stats + 16-step sigmoid long-division reciprocal ----------
// E fp16 (BQ x NK), E = exp(s - EXP_BIAS). Per row: T = sum(E), mx = max(E) = e^(m-4).
// d = 1 + T/mx  (== 1 + sum(exp(s-m)) exactly);  q = scan(d);  factor = q/mx.
// One wave per row, 4 rows/block, no LDS.

__global__ __launch_bounds__(256)
void row_stats(const u16* __restrict__ E, float* __restrict__ factor) {
    const int lane = threadIdx.x & 63;
    const int row  = blockIdx.x * 4 + (threadIdx.x >> 6);

    const u16x8* sp = reinterpret_cast<const u16x8*>(E + (size_t)row * NK);
    u16x8 raw[4];
#pragma unroll
    for (int j = 0; j < 4; ++j) raw[j] = sp[lane + j * 64];   // coalesced 16B/lane

    float T = 0.f, mx = 0.f;
#pragma unroll
    for (int j = 0; j < 4; ++j)
#pragma unroll
        for (int i = 0; i < 8; ++i) {
            float f = (float)__builtin_bit_cast(_Float16, (unsigned short)raw[j][i]);
            T += f;
            mx = fmaxf(mx, f);
        }
#pragma unroll
    for (int off = 32; off; off >>= 1) {
        T  += __shfl_xor(T, off);
        mx  = fmaxf(mx, __shfl_xor(mx, off));
    }

    const float d = 1.0f + T / mx;

    // non-restoring long division, 16 bits, soft comparator sigmoid(100*(2r - d))
    float r = 1.0f, q = 0.0f, w = 0.5f;
#pragma unroll
    for (int i = 0; i < 16; ++i) {
        float doubled = 2.0f * r;
        float st = 1.0f / (1.0f + expf(-100.0f * (doubled - d)));
        r = doubled - d * st;
        q += w * st;
        w *= 0.5f;
    }

    if (lane == 0) factor[row] = q / mx;
}

// ---------- launch ----------

extern "C" void kernel_launch(void* const* d_in, const int* in_sizes, int n_in,
                              void* d_out, int out_size, void* d_ws, size_t ws_size,
                              hipStream_t stream) {
    const float* Q = (const float*)d_in[0];
    const float* K = (const float*)d_in[1];
    const float* V = (const float*)d_in[2];
    float* out = (float*)d_out;

    char* ws = (char*)d_ws;
    // ws layout (bytes):
    //   Qb  bf16 8192x1024 : 16 MiB
    //   Kb  bf16 2048x1024 :  4 MiB
    //   VhT fp16 1024x2048 :  4 MiB
    //   E   fp16 8192x2048 : 32 MiB  (exp(s-4))
    //   factor f32 8192    : 32 KiB  -> total ~56 MiB
    u16*   Qb     = (u16*)(ws);
    u16*   Kb     = (u16*)(ws + (16u << 20));
    u16*   VhT    = (u16*)(ws + (20u << 20));
    u16*   E      = (u16*)(ws + (24u << 20));
    float* factor = (float*)(ws + (56u << 20));

    // stage 0: converts (Q+K fused) and V transpose
    {
        int n4Q = BQ * DIM / 4;
        int n4T = n4Q + NK * DIM / 4;
        cvt_qk<<<(n4T + 255) / 256, 256, 0, stream>>>(Q, K, Qb, Kb, n4Q, n4T);
    }
    transpose_cvt<<<dim3(DIM / 32, NK / 32), dim3(32, 8), 0, stream>>>(V, VhT);

    // stage 1: E = exp(QK^T/32 - 4) fp16   (M=8192, N=2048, K=1024) — 256 blocks
    gemm256<256, false, true, _Float16><<<(BQ / 256) * (NK / 256), 512, 0, stream>>>(
        Qb, Kb, (_Float16*)E, nullptr, DIM, DIM, DIM, NK, 0.03125f, NK / 256);

    // stage 2: per-row stats + reciprocal scan -> factor[row] = q/maxE
    row_stats<<<BQ / 4, 256, 0, stream>>>(E, factor);

    // stage 3: out = (E @ VhT^T) * factor[row]  (M=8192, N=1024, K=2048) — 256 blocks
    gemm256<128, true, false, float><<<(BQ / 256) * (DIM / 128), 512, 0, stream>>>(
        E, VhT, out, factor, NK, NK, NK, DIM, 1.0f, DIM / 128);
}